// Round 13
// baseline (580.477 us; speedup 1.0000x reference)
//
#include <hip/hip_runtime.h>
#include <float.h>

#define KC 4096
#define DIM 256
#define MB 16384            // m per batch element (16*32*32)
#define NTOT 65536          // rows
#define ZELEMS 16777216
#define LOSS_OFF 16777216
#define IDX_OFF  16777217
// TAU: 2*(grid ULP(256)=3.05e-5) + 2*fp16-chain score err (<=4.7e-5 worst) + slack.
// Validated empirically at 1.5e-4 in R11/R12 (0 misses across 65536 rows).
#define TAU 1.5e-4f
#define NSPLIT 4            // K-split factor (1024 codes per block)

// scratch inside z_q output region (fully overwritten by vq_apply at the end):
// [0, 524288)       fp16 e' A-fragment table (2MB)
#define BT_OFF   524288     // f32 |e_k|^2 table, 4096 floats
#define CNT_OFF  528400     // 2 uints (cand count, full count)
#define CAND_OFF 532480     // uint4 entries (16B each), cap 65536 -> ends 794624
#define FULL_OFF 800000     // uint entries, cap 65536 -> ends 865536
#define PART_OFF 900000     // partial top-5: [split][row][8] floats = 2M floats

typedef _Float16 h8 __attribute__((ext_vector_type(8)));
typedef float f4v __attribute__((ext_vector_type(4)));

__device__ __forceinline__ bool lexlt(float av, int ai, float bv, int bi) {
    return (av < bv) || (av == bv && ai < bi);
}

// ---- P1: |e_k|^2 table (fp64 -> f32), one wave per code ----
__global__ __launch_bounds__(256) void vq_prep_b(const float* __restrict__ e,
                                                 float* __restrict__ out) {
    int k = blockIdx.x * 4 + (threadIdx.x >> 6);
    int lane = threadIdx.x & 63;
    float4 v = reinterpret_cast<const float4*>(e + (size_t)k * DIM)[lane];
    double s = (double)v.x * v.x + (double)v.y * v.y + (double)v.z * v.z + (double)v.w * v.w;
    #pragma unroll
    for (int off = 32; off > 0; off >>= 1) s += __shfl_down(s, off);
    if (lane == 0) out[BT_OFF + k] = (float)s;
}

// ---- P2: e' = e*4096 -> fp16 A-fragment table (R10-R12-verified geometry) ----
__global__ __launch_bounds__(256) void vq_prep_e(const float* __restrict__ e,
                                                 float* __restrict__ out) {
    int t = blockIdx.x * 256 + threadIdx.x;        // 0..131071
    int code = t >> 5, s8 = t & 31;
    const float4* src = reinterpret_cast<const float4*>(e + (size_t)code * DIM + s8 * 8);
    float4 v0 = src[0], v1 = src[1];
    float f[8] = {v0.x, v0.y, v0.z, v0.w, v1.x, v1.y, v1.z, v1.w};
    union { uint4 q; _Float16 h[8]; } P;
    #pragma unroll
    for (int p = 0; p < 8; ++p) P.h[p] = (_Float16)(f[p] * 4096.0f);
    int kc = s8 >> 2, khi = s8 & 3;
    int lane = khi * 16 + (code & 15);
    int slot = ((code >> 4) * 8 + kc) * 64 + lane;
    reinterpret_cast<uint4*>(out)[slot] = P.q;
}

// depth-5 sorted insert (indices through slot 4); strict < keeps first-index rule
#define INS5(s, k, B1, I1, B2, I2, B3, I3, B4, I4, B5)                          \
    if (s < B5) {                                                               \
        if (s < B3) {                                                           \
            if (s < B2) {                                                       \
                if (s < B1) { B5=B4; B4=B3; I4=I3; B3=B2; I3=I2; B2=B1; I2=I1; B1=s; I1=k; } \
                else        { B5=B4; B4=B3; I4=I3; B3=B2; I3=I2; B2=s; I2=k; }  \
            } else          { B5=B4; B4=B3; I4=I3; B3=s; I3=k; }                \
        } else {                                                                \
            if (s < B4)     { B5=B4; B4=s; I4=k; }                              \
            else            { B5=s; }                                           \
        }                                                                       \
    }

// one pop step of the sorted-5 merge (a-list by ref, c-list local copies)
#define POPSTEP(rv, riv)                                                        \
    {                                                                           \
        bool t = lexlt(a1, ai1, c1, ci1);                                       \
        rv = t ? a1 : c1; riv = t ? ai1 : ci1;                                  \
        a1 = t ? a2 : a1;  ai1 = t ? ai2 : ai1;                                 \
        a2 = t ? a3 : a2;  ai2 = t ? ai3 : ai2;                                 \
        a3 = t ? a4 : a3;  ai3 = t ? ai4 : ai3;                                 \
        a4 = t ? a5 : a4;  ai4 = t ? 0x7FFFFFFF : ai4;                          \
        a5 = t ? FLT_MAX : a5;                                                  \
        c1 = t ? c1 : c2;  ci1 = t ? ci1 : ci2;                                 \
        c2 = t ? c2 : c3;  ci2 = t ? ci2 : ci3;                                 \
        c3 = t ? c3 : c4;  ci3 = t ? ci3 : ci4;                                 \
        c4 = t ? c4 : c5;  ci4 = t ? ci4 : 0x7FFFFFFF;                          \
        c5 = t ? c5 : FLT_MAX;                                                  \
    }

__device__ __forceinline__ void merge5(float& a1, int& ai1, float& a2, int& ai2,
                                       float& a3, int& ai3, float& a4, int& ai4, float& a5,
                                       float c1, int ci1, float c2, int ci2,
                                       float c3, int ci3, float c4, int ci4, float c5) {
    float r1, r2, r3, r4; int ri1, ri2, ri3, ri4;
    POPSTEP(r1, ri1)
    POPSTEP(r2, ri2)
    POPSTEP(r3, ri3)
    POPSTEP(r4, ri4)
    float r5 = fminf(a1, c1);
    a1 = r1; ai1 = ri1; a2 = r2; ai2 = ri2; a3 = r3; ai3 = ri3; a4 = r4; ai4 = ri4; a5 = r5;
}

// ---- K1: fp16 MFMA fast pass, top-5, K-split. Block = 128 rows x 1024 codes. ----
__global__ __launch_bounds__(256) void vq_fast(const float* __restrict__ z,
                                               float* __restrict__ out) {
    __shared__ uint4 etile[512];                   // 8KB, one 16-code tile of A-frags
    const int tid = threadIdx.x;
    const int wave = tid >> 6, lane = tid & 63;
    const int khi = lane >> 4, l16 = lane & 15;
    const int split = blockIdx.x & (NSPLIT - 1);
    const int rb = blockIdx.x / NSPLIT;
    const int nbase = rb * 128;
    const int b = nbase / MB;
    const int mbase = nbase % MB;
    const float* zb = z + (size_t)b * DIM * MB + mbase + wave * 32 + l16;
    const int t0 = split * (KC / 16 / NSPLIT);     // 64 tiles per split

    // z B-fragments (fp16), 2 row-sets x 8 kc
    h8 zf0[8], zf1[8];
    #pragma unroll
    for (int kc = 0; kc < 8; ++kc) {
        h8 va, vb;
        #pragma unroll
        for (int j = 0; j < 8; ++j) {
            size_t off = (size_t)(kc * 32 + khi * 8 + j) * MB;
            va[j] = (_Float16)zb[off];
            vb[j] = (_Float16)zb[off + 16];
        }
        zf0[kc] = va; zf1[kc] = vb;
    }

    const uint4* ET = reinterpret_cast<const uint4*>(out);
    const float* Btab = out + BT_OFF;

    float b10 = FLT_MAX, b20 = FLT_MAX, b30 = FLT_MAX, b40 = FLT_MAX, b50 = FLT_MAX;
    float b11 = FLT_MAX, b21 = FLT_MAX, b31 = FLT_MAX, b41 = FLT_MAX, b51 = FLT_MAX;
    int i10 = 0, i20 = 0, i30 = 0, i40 = 0;
    int i11 = 0, i21 = 0, i31 = 0, i41 = 0;

    uint4 r0 = ET[(size_t)t0 * 512 + tid];
    uint4 r1 = ET[(size_t)t0 * 512 + tid + 256];

    for (int tile = t0; tile < t0 + KC / 16 / NSPLIT; ++tile) {
        etile[tid] = r0; etile[tid + 256] = r1;
        __syncthreads();
        if (tile < t0 + KC / 16 / NSPLIT - 1) {
            r0 = ET[(size_t)(tile + 1) * 512 + tid];
            r1 = ET[(size_t)(tile + 1) * 512 + tid + 256];
        }

        f4v a0 = {0.f, 0.f, 0.f, 0.f}, a1 = a0;
        #pragma unroll
        for (int kc = 0; kc < 8; ++kc) {
            union { uint4 q; h8 v; } af;
            af.q = etile[kc * 64 + lane];
            a0 = __builtin_amdgcn_mfma_f32_16x16x32_f16(af.v, zf0[kc], a0, 0, 0, 0);
            a1 = __builtin_amdgcn_mfma_f32_16x16x32_f16(af.v, zf1[kc], a1, 0, 0, 0);
        }

        const f4v Bv = *reinterpret_cast<const f4v*>(Btab + tile * 16 + khi * 4);
        #pragma unroll
        for (int i = 0; i < 4; ++i) {
            int k = tile * 16 + khi * 4 + i;       // ascending per lane
            float s0 = fmaf(-4.8828125e-4f, a0[i], Bv[i]);  // -1/2048 exact
            float s1 = fmaf(-4.8828125e-4f, a1[i], Bv[i]);
            INS5(s0, k, b10, i10, b20, i20, b30, i30, b40, i40, b50)
            INS5(s1, k, b11, i11, b21, i21, b31, i31, b41, i41, b51)
        }
        __syncthreads();
    }

    // merge the 4 khi code-groups (lanes sharing l16 = same z-row)
    #pragma unroll
    for (int off = 16; off < 64; off <<= 1) {
        merge5(b10, i10, b20, i20, b30, i30, b40, i40, b50,
               __shfl_xor(b10, off), __shfl_xor(i10, off),
               __shfl_xor(b20, off), __shfl_xor(i20, off),
               __shfl_xor(b30, off), __shfl_xor(i30, off),
               __shfl_xor(b40, off), __shfl_xor(i40, off), __shfl_xor(b50, off));
        merge5(b11, i11, b21, i21, b31, i31, b41, i41, b51,
               __shfl_xor(b11, off), __shfl_xor(i11, off),
               __shfl_xor(b21, off), __shfl_xor(i21, off),
               __shfl_xor(b31, off), __shfl_xor(i31, off),
               __shfl_xor(b41, off), __shfl_xor(i41, off), __shfl_xor(b51, off));
    }
    if (lane < 16) {
        int row0 = nbase + wave * 32 + l16;
        size_t base0 = (size_t)PART_OFF + ((size_t)(split << 16) + row0) * 8;
        *reinterpret_cast<float4*>(out + base0) = make_float4(b10, b20, b30, b40);
        *reinterpret_cast<float4*>(out + base0 + 4) =
            make_float4(b50, (float)(i10 + (i20 << 12)), (float)(i30 + (i40 << 12)), 0.f);
        size_t base1 = base0 + 16 * 8;
        *reinterpret_cast<float4*>(out + base1) = make_float4(b11, b21, b31, b41);
        *reinterpret_cast<float4*>(out + base1 + 4) =
            make_float4(b51, (float)(i11 + (i21 << 12)), (float)(i31 + (i41 << 12)), 0.f);
    }
}

// ---- K1b: merge the NSPLIT partial top-5s per row, classify, emit ----
__global__ __launch_bounds__(256) void vq_merge(float* __restrict__ out) {
    const int r = blockIdx.x * 256 + threadIdx.x;
    const int lane = threadIdx.x & 63;
    const float* P = out + PART_OFF + (size_t)r * 8;
    float4 pa = *reinterpret_cast<const float4*>(P);
    float4 pb = *reinterpret_cast<const float4*>(P + 4);
    float B1 = pa.x, B2 = pa.y, B3 = pa.z, B4 = pa.w, B5 = pb.x;
    int p12 = (int)pb.y, p34 = (int)pb.z;
    int I1 = p12 & 4095, I2 = p12 >> 12, I3 = p34 & 4095, I4 = p34 >> 12;
    #pragma unroll
    for (int j = 1; j < NSPLIT; ++j) {
        const float* Q = out + PART_OFF + ((size_t)(j << 16) + r) * 8;
        float4 qa = *reinterpret_cast<const float4*>(Q);
        float4 qb = *reinterpret_cast<const float4*>(Q + 4);
        int q12 = (int)qb.y, q34 = (int)qb.z;
        merge5(B1, I1, B2, I2, B3, I3, B4, I4, B5,
               qa.x, q12 & 4095, qa.y, q12 >> 12, qa.z, q34 & 4095, qa.w, q34 >> 12, qb.x);
    }
    // classify + emit (wave-aggregated atomics)
    bool clean = (B2 > B1 + TAU);
    bool cand  = !clean && (B5 > B1 + TAU);
    bool full  = !clean && !cand;
    out[IDX_OFF + r] = (float)I1;                  // final for clean; placeholder else
    unsigned* cnt = (unsigned*)(out + CNT_OFF);
    unsigned long long mc = __ballot(cand);
    if (mc) {
        int leader = __ffsll((long long)mc) - 1;
        unsigned base = 0;
        if (lane == leader) base = atomicAdd(cnt, (unsigned)__popcll(mc));
        base = __shfl(base, leader);
        if (cand) {
            unsigned pos = base + (unsigned)__popcll(mc & ((1ull << lane) - 1ull));
            reinterpret_cast<uint4*>(out + CAND_OFF)[pos] =
                make_uint4((unsigned)r,
                           (unsigned)I1 | ((unsigned)I2 << 16),
                           (unsigned)I3 | ((unsigned)I4 << 16), 0u);
        }
    }
    unsigned long long mf = __ballot(full);
    if (mf) {
        int leader = __ffsll((long long)mf) - 1;
        unsigned base = 0;
        if (lane == leader) base = atomicAdd(cnt + 1, (unsigned)__popcll(mf));
        base = __shfl(base, leader);
        if (full) {
            unsigned pos = base + (unsigned)__popcll(mf & ((1ull << lane) - 1ull));
            reinterpret_cast<unsigned*>(out + FULL_OFF)[pos] = (unsigned)r;
        }
    }
}

// ---- K2a: candidate rescore (<=4 codes), grid-stride waves over cand list ----
__global__ __launch_bounds__(256) void vq_resolve_cand(const float* __restrict__ z,
                                                       const float* __restrict__ e,
                                                       float* __restrict__ out) {
    const int wave = threadIdx.x >> 6, lane = threadIdx.x & 63;
    const unsigned n = *reinterpret_cast<const unsigned*>(out + CNT_OFF);
    const uint4* list = reinterpret_cast<const uint4*>(out + CAND_OFF);
    for (unsigned ei = blockIdx.x * 4 + wave; ei < n; ei += gridDim.x * 4) {
        uint4 ent = list[ei];
        const int gidx = (int)ent.x;
        const int c1 = (int)(ent.y & 0xFFFFu), c2 = (int)(ent.y >> 16);
        const int c3 = (int)(ent.z & 0xFFFFu), c4 = (int)(ent.z >> 16);
        const int b = gidx >> 14, m = gidx & (MB - 1);
        const float* zr = z + (size_t)b * DIM * MB + m;
        const float* e1 = e + (size_t)c1 * DIM;
        const float* e2 = e + (size_t)c2 * DIM;
        const float* e3 = e + (size_t)c3 * DIM;
        const float* e4 = e + (size_t)c4 * DIM;
        double A = 0.0;
        double d1 = 0.0, d2 = 0.0, d3 = 0.0, d4 = 0.0;
        double q1 = 0.0, q2 = 0.0, q3 = 0.0, q4 = 0.0;
        #pragma unroll
        for (int jj = 0; jj < 4; ++jj) {
            int d = lane * 4 + jj;
            double zv = (double)zr[(size_t)d * MB];
            double v1 = (double)e1[d], v2 = (double)e2[d];
            double v3 = (double)e3[d], v4 = (double)e4[d];
            A = fma(zv, zv, A);
            d1 = fma(zv, v1, d1); q1 = fma(v1, v1, q1);
            d2 = fma(zv, v2, d2); q2 = fma(v2, v2, q2);
            d3 = fma(zv, v3, d3); q3 = fma(v3, v3, q3);
            d4 = fma(zv, v4, d4); q4 = fma(v4, v4, q4);
        }
        #pragma unroll
        for (int mm = 1; mm < 64; mm <<= 1) {
            A += __shfl_xor(A, mm);
            d1 += __shfl_xor(d1, mm); q1 += __shfl_xor(q1, mm);
            d2 += __shfl_xor(d2, mm); q2 += __shfl_xor(q2, mm);
            d3 += __shfl_xor(d3, mm); q3 += __shfl_xor(q3, mm);
            d4 += __shfl_xor(d4, mm); q4 += __shfl_xor(q4, mm);
        }
        if (lane == 0) {
            float Af = (float)A;
            float s1 = (Af - (float)(2.0 * d1)) + (float)q1;
            float s2 = (Af - (float)(2.0 * d2)) + (float)q2;
            float s3 = (Af - (float)(2.0 * d3)) + (float)q3;
            float s4 = (Af - (float)(2.0 * d4)) + (float)q4;
            float bv = s1; int bk = c1;
            if (lexlt(s2, c2, bv, bk)) { bv = s2; bk = c2; }
            if (lexlt(s3, c3, bv, bk)) { bv = s3; bk = c3; }
            if (lexlt(s4, c4, bv, bk)) { bv = s4; bk = c4; }
            out[IDX_OFF + gidx] = (float)bk;
        }
    }
}

// ---- K2b: full exact rescan, grid-stride blocks over full list ----
__global__ __launch_bounds__(256) void vq_resolve_full(const float* __restrict__ z,
                                                       const float* __restrict__ e,
                                                       float* __restrict__ out) {
    __shared__ float zs[DIM];
    __shared__ float rv[4];
    __shared__ int ri[4];
    const int tid = threadIdx.x;
    const int wave = tid >> 6, lane = tid & 63;
    const unsigned n = reinterpret_cast<const unsigned*>(out + CNT_OFF)[1];
    const unsigned* list = reinterpret_cast<const unsigned*>(out + FULL_OFF);
    for (unsigned ei = blockIdx.x; ei < n; ei += gridDim.x) {
        const int gidx = (int)list[ei];
        const int b = gidx >> 14, m = gidx & (MB - 1);
        const float* zr = z + (size_t)b * DIM * MB + m;
        if (tid < DIM) zs[tid] = zr[(size_t)tid * MB];
        __syncthreads();
        double av = 0.0;
        #pragma unroll
        for (int t2 = 0; t2 < 4; ++t2) {
            double zv = (double)zs[lane * 4 + t2];
            av = fma(zv, zv, av);
        }
        #pragma unroll
        for (int mm = 1; mm < 64; mm <<= 1) av += __shfl_xor(av, mm);
        const float Af = (float)av;

        float bsv = FLT_MAX; int bsk = 0;
        for (int kk = 0; kk < 16; ++kk) {
            const int k = kk * 256 + tid;          // ascending per thread
            const float4* er4 = reinterpret_cast<const float4*>(e + (size_t)k * DIM);
            const float4* zs4 = reinterpret_cast<const float4*>(zs);
            double dot0 = 0.0, dot1 = 0.0, q0 = 0.0, q1 = 0.0;
            #pragma unroll 8
            for (int d4 = 0; d4 < 64; ++d4) {
                float4 ev = er4[d4];
                float4 zv = zs4[d4];
                dot0 = fma((double)zv.x, (double)ev.x, dot0);
                dot1 = fma((double)zv.y, (double)ev.y, dot1);
                dot0 = fma((double)zv.z, (double)ev.z, dot0);
                dot1 = fma((double)zv.w, (double)ev.w, dot1);
                q0 = fma((double)ev.x, (double)ev.x, q0);
                q1 = fma((double)ev.y, (double)ev.y, q1);
                q0 = fma((double)ev.z, (double)ev.z, q0);
                q1 = fma((double)ev.w, (double)ev.w, q1);
            }
            float s = (Af - (float)(2.0 * (dot0 + dot1))) + (float)(q0 + q1);
            if (s < bsv) { bsv = s; bsk = k; }
        }
        #pragma unroll
        for (int mm = 1; mm < 64; mm <<= 1) {
            float ov = __shfl_xor(bsv, mm);
            int oi = __shfl_xor(bsk, mm);
            if (ov < bsv || (ov == bsv && oi < bsk)) { bsv = ov; bsk = oi; }
        }
        if (lane == 0) { rv[wave] = bsv; ri[wave] = bsk; }
        __syncthreads();
        if (tid == 0) {
            float bv = rv[0]; int bk = ri[0];
            #pragma unroll
            for (int wv = 1; wv < 4; ++wv) {
                if (rv[wv] < bv || (rv[wv] == bv && ri[wv] < bk)) { bv = rv[wv]; bk = ri[wv]; }
            }
            out[IDX_OFF + gidx] = (float)bk;
        }
        __syncthreads();
    }
}

// ---- K3: z_q scatter + fused loss; e-rows staged in LDS (coalesced) ----
__global__ __launch_bounds__(256) void vq_apply(const float* __restrict__ z,
                                                const float* __restrict__ e,
                                                float* __restrict__ out) {
    __shared__ int lds_fi[64];
    __shared__ float lds_e[64][260];
    __shared__ double lds_ls[4];
    const int tid = threadIdx.x;
    const int wave = tid >> 6, lane = tid & 63;
    const int nbase = blockIdx.x * 64;
    const int b = nbase / MB;
    const int mbase = nbase % MB;
    if (tid < 64) lds_fi[tid] = (int)out[IDX_OFF + nbase + tid];
    __syncthreads();
    for (int r = wave; r < 64; r += 4) {
        int code = lds_fi[r];
        float4 v = reinterpret_cast<const float4*>(e + (size_t)code * DIM)[lane];
        *reinterpret_cast<float4*>(&lds_e[r][lane * 4]) = v;
    }
    __syncthreads();

    double lsum = 0.0;
    const int mloc = tid & 63;
    const int d0 = tid >> 6;
    #pragma unroll 4
    for (int d = d0; d < DIM; d += 4) {
        float ev = lds_e[mloc][d];
        size_t off = (size_t)b * (DIM * MB) + (size_t)d * MB + mbase + mloc;
        float zv = z[off];
        out[off] = ev;
        float diff = ev - zv;
        lsum += (double)diff * diff;
    }
    #pragma unroll
    for (int off = 32; off > 0; off >>= 1) lsum += __shfl_down(lsum, off);
    if (lane == 0) lds_ls[wave] = lsum;
    __syncthreads();
    if (tid == 0) {
        double t = lds_ls[0] + lds_ls[1] + lds_ls[2] + lds_ls[3];
        atomicAdd(out + LOSS_OFF, (float)(t * (1.25 / (double)ZELEMS)));
    }
}

extern "C" void kernel_launch(void* const* d_in, const int* in_sizes, int n_in,
                              void* d_out, int out_size, void* d_ws, size_t ws_size,
                              hipStream_t stream) {
    const float* z = (const float*)d_in[0];    // [4,256,16,32,32] fp32
    const float* e = (const float*)d_in[1];    // [4096,256] fp32
    float* out = (float*)d_out;

    hipMemsetAsync(out + LOSS_OFF, 0, sizeof(float), stream);
    hipMemsetAsync(out + CNT_OFF, 0, 2 * sizeof(unsigned), stream);
    vq_prep_b<<<KC / 4, 256, 0, stream>>>(e, out);
    vq_prep_e<<<512, 256, 0, stream>>>(e, out);
    vq_fast<<<(NTOT / 128) * NSPLIT, 256, 0, stream>>>(z, out);
    vq_merge<<<NTOT / 256, 256, 0, stream>>>(out);
    vq_resolve_cand<<<256, 256, 0, stream>>>(z, e, out);
    vq_resolve_full<<<512, 256, 0, stream>>>(z, e, out);
    vq_apply<<<NTOT / 64, 256, 0, stream>>>(z, e, out);
}

// Round 15
// 573.600 us; speedup vs baseline: 1.0120x; 1.0120x over previous
//
#include <hip/hip_runtime.h>
#include <float.h>

#define KC 4096
#define DIM 256
#define MB 16384            // m per batch element (16*32*32)
#define NTOT 65536          // rows
#define ZELEMS 16777216
#define LOSS_OFF 16777216
#define IDX_OFF  16777217
// TAU: 2*(grid ULP(256)=3.05e-5) + 2*fp16-chain score err (<=4.7e-5 worst) + slack.
// Validated empirically at 1.5e-4 in R11-R13 (0 misses across 65536 rows).
#define TAU 1.5e-4f

// scratch inside z_q output region (fully overwritten by vq_apply at the end):
// [0, 524288)       fp16 e' A-fragment table (2MB)
#define BT_OFF   524288     // f32 |e_k|^2 table, 4096 floats
#define CNT_OFF  528400     // 2 uints (cand count, full count)
#define CAND_OFF 532480     // uint4 entries (16B each), cap 65536
#define FULL_OFF 800000     // uint entries, cap 65536

typedef _Float16 h8 __attribute__((ext_vector_type(8)));
typedef float f4v __attribute__((ext_vector_type(4)));

__device__ __forceinline__ bool lexlt(float av, int ai, float bv, int bi) {
    return (av < bv) || (av == bv && ai < bi);
}

// ---- P: fused prep. Blocks 0-511: fp16 e'=e*4096 A-frag table (R10-R13
// verified geometry). Blocks 512-1535: |e|^2 (fp64->f32), one wave per code
// (1024 blocks x 4 waves = 4096 codes — R14 launched only 256 here: BUG). ----
__global__ __launch_bounds__(256) void vq_prep(const float* __restrict__ e,
                                               float* __restrict__ out) {
    if (blockIdx.x < 512) {
        int t = blockIdx.x * 256 + threadIdx.x;        // 0..131071
        int code = t >> 5, s8 = t & 31;
        const float4* src = reinterpret_cast<const float4*>(e + (size_t)code * DIM + s8 * 8);
        float4 v0 = src[0], v1 = src[1];
        float f[8] = {v0.x, v0.y, v0.z, v0.w, v1.x, v1.y, v1.z, v1.w};
        union { uint4 q; _Float16 h[8]; } P;
        #pragma unroll
        for (int p = 0; p < 8; ++p) P.h[p] = (_Float16)(f[p] * 4096.0f);
        int kc = s8 >> 2, khi = s8 & 3;
        int lane = khi * 16 + (code & 15);
        int slot = ((code >> 4) * 8 + kc) * 64 + lane;
        reinterpret_cast<uint4*>(out)[slot] = P.q;
    } else {
        int k = (blockIdx.x - 512) * 4 + (threadIdx.x >> 6);   // 0..4095
        int lane = threadIdx.x & 63;
        float4 v = reinterpret_cast<const float4*>(e + (size_t)k * DIM)[lane];
        double s = (double)v.x * v.x + (double)v.y * v.y + (double)v.z * v.z + (double)v.w * v.w;
        #pragma unroll
        for (int off = 32; off > 0; off >>= 1) s += __shfl_down(s, off);
        if (lane == 0) out[BT_OFF + k] = (float)s;
    }
}

// ---- K1: fp16 MFMA, TWO-PASS exact-window. Block = 128 rows (4w x 32r). ----
// Pass 1: exact top-1 (hierarchical filter, strict-< first-index).
// Pass 2: recompute (bitwise-same), collect ALL scores <= b1+TAU.
// Classes: |W|==1 clean; 2..4 cand (complete list); >=5 full.
__global__ __launch_bounds__(256) void vq_fast(const float* __restrict__ z,
                                               float* __restrict__ out) {
    __shared__ uint4 etile[2][512];                // 16KB double-buffered tile
    __shared__ unsigned long long lists[4][32][4]; // per (wave,row,khi) packed W-list
    const int tid = threadIdx.x;
    const int wave = tid >> 6, lane = tid & 63;
    const int khi = lane >> 4, l16 = lane & 15;
    const int nbase = blockIdx.x * 128;
    const int b = nbase / MB;
    const int mbase = nbase % MB;
    const float* zb = z + (size_t)b * DIM * MB + mbase + wave * 32 + l16;

    // z B-fragments (fp16), 2 row-sets x 8 kc
    h8 zf0[8], zf1[8];
    #pragma unroll
    for (int kc = 0; kc < 8; ++kc) {
        h8 va, vb;
        #pragma unroll
        for (int j = 0; j < 8; ++j) {
            size_t off = (size_t)(kc * 32 + khi * 8 + j) * MB;
            va[j] = (_Float16)zb[off];
            vb[j] = (_Float16)zb[off + 16];
        }
        zf0[kc] = va; zf1[kc] = vb;
    }

    const uint4* ET = reinterpret_cast<const uint4*>(out);
    const float* Btab = out + BT_OFF;

    // ---------------- pass 1: top-1 ----------------
    float b1f0 = FLT_MAX, b1f1 = FLT_MAX;
    int k10 = 0, k11 = 0;
    {
        uint4 r0 = ET[tid], r1 = ET[tid + 256];
        for (int tile = 0; tile < KC / 16; ++tile) {
            const int cur = tile & 1;
            etile[cur][tid] = r0; etile[cur][tid + 256] = r1;
            __syncthreads();
            if (tile < KC / 16 - 1) {
                r0 = ET[(size_t)(tile + 1) * 512 + tid];
                r1 = ET[(size_t)(tile + 1) * 512 + tid + 256];
            }
            f4v a0 = {0.f, 0.f, 0.f, 0.f}, a1 = a0;
            #pragma unroll
            for (int kc = 0; kc < 8; ++kc) {
                union { uint4 q; h8 v; } af;
                af.q = etile[cur][kc * 64 + lane];
                a0 = __builtin_amdgcn_mfma_f32_16x16x32_f16(af.v, zf0[kc], a0, 0, 0, 0);
                a1 = __builtin_amdgcn_mfma_f32_16x16x32_f16(af.v, zf1[kc], a1, 0, 0, 0);
            }
            const f4v Bv = *reinterpret_cast<const f4v*>(Btab + tile * 16 + khi * 4);
            float s0[4], s1[4];
            #pragma unroll
            for (int i = 0; i < 4; ++i) {
                s0[i] = fmaf(-4.8828125e-4f, a0[i], Bv[i]);   // -1/2048 exact
                s1[i] = fmaf(-4.8828125e-4f, a1[i], Bv[i]);
            }
            const int kb = tile * 16 + khi * 4;
            float m0 = fminf(fminf(s0[0], s0[1]), fminf(s0[2], s0[3]));
            if (m0 < b1f0) {                       // rare: detail, strict <, ascending i
                #pragma unroll
                for (int i = 0; i < 4; ++i)
                    if (s0[i] < b1f0) { b1f0 = s0[i]; k10 = kb + i; }
            }
            float m1 = fminf(fminf(s1[0], s1[1]), fminf(s1[2], s1[3]));
            if (m1 < b1f1) {
                #pragma unroll
                for (int i = 0; i < 4; ++i)
                    if (s1[i] < b1f1) { b1f1 = s1[i]; k11 = kb + i; }
            }
        }
    }
    // merge top-1 across the 4 khi groups (lex: value then index)
    #pragma unroll
    for (int off = 16; off < 64; off <<= 1) {
        float ov = __shfl_xor(b1f0, off); int ok = __shfl_xor(k10, off);
        if (lexlt(ov, ok, b1f0, k10)) { b1f0 = ov; k10 = ok; }
        ov = __shfl_xor(b1f1, off); ok = __shfl_xor(k11, off);
        if (lexlt(ov, ok, b1f1, k11)) { b1f1 = ov; k11 = ok; }
    }
    const float thr0 = b1f0 + TAU, thr1 = b1f1 + TAU;

    // ---------------- pass 2: exact window collect ----------------
    int cnt0 = 0, ca0 = 0, cb0 = 0, cc0 = 0, cd0 = 0;
    int cnt1 = 0, ca1 = 0, cb1 = 0, cc1 = 0, cd1 = 0;
    {
        uint4 r0 = ET[tid], r1 = ET[tid + 256];
        __syncthreads();                            // pass1's last reads done
        for (int tile = 0; tile < KC / 16; ++tile) {
            const int cur = tile & 1;
            etile[cur][tid] = r0; etile[cur][tid + 256] = r1;
            __syncthreads();
            if (tile < KC / 16 - 1) {
                r0 = ET[(size_t)(tile + 1) * 512 + tid];
                r1 = ET[(size_t)(tile + 1) * 512 + tid + 256];
            }
            f4v a0 = {0.f, 0.f, 0.f, 0.f}, a1 = a0;
            #pragma unroll
            for (int kc = 0; kc < 8; ++kc) {
                union { uint4 q; h8 v; } af;
                af.q = etile[cur][kc * 64 + lane];
                a0 = __builtin_amdgcn_mfma_f32_16x16x32_f16(af.v, zf0[kc], a0, 0, 0, 0);
                a1 = __builtin_amdgcn_mfma_f32_16x16x32_f16(af.v, zf1[kc], a1, 0, 0, 0);
            }
            const f4v Bv = *reinterpret_cast<const f4v*>(Btab + tile * 16 + khi * 4);
            float s0[4], s1[4];
            #pragma unroll
            for (int i = 0; i < 4; ++i) {
                s0[i] = fmaf(-4.8828125e-4f, a0[i], Bv[i]);
                s1[i] = fmaf(-4.8828125e-4f, a1[i], Bv[i]);
            }
            const int kb = tile * 16 + khi * 4;
            float m0 = fminf(fminf(s0[0], s0[1]), fminf(s0[2], s0[3]));
            if (m0 <= thr0) {                      // rare: collect members
                #pragma unroll
                for (int i = 0; i < 4; ++i)
                    if (s0[i] <= thr0) {
                        int k = kb + i;
                        if (cnt0 == 0) ca0 = k; else if (cnt0 == 1) cb0 = k;
                        else if (cnt0 == 2) cc0 = k; else if (cnt0 == 3) cd0 = k;
                        cnt0++;
                    }
            }
            float m1 = fminf(fminf(s1[0], s1[1]), fminf(s1[2], s1[3]));
            if (m1 <= thr1) {
                #pragma unroll
                for (int i = 0; i < 4; ++i)
                    if (s1[i] <= thr1) {
                        int k = kb + i;
                        if (cnt1 == 0) ca1 = k; else if (cnt1 == 1) cb1 = k;
                        else if (cnt1 == 2) cc1 = k; else if (cnt1 == 3) cd1 = k;
                        cnt1++;
                    }
            }
        }
    }
    // pack per-lane lists: 4x12b ks + 8b cnt (saturate 15)
    unsigned long long p0 = (unsigned long long)(cnt0 > 15 ? 15 : cnt0) << 48 |
        (unsigned long long)ca0 | ((unsigned long long)cb0 << 12) |
        ((unsigned long long)cc0 << 24) | ((unsigned long long)cd0 << 36);
    unsigned long long p1 = (unsigned long long)(cnt1 > 15 ? 15 : cnt1) << 48 |
        (unsigned long long)ca1 | ((unsigned long long)cb1 << 12) |
        ((unsigned long long)cc1 << 24) | ((unsigned long long)cd1 << 36);
    lists[wave][l16][khi] = p0;
    lists[wave][16 + l16][khi] = p1;
    __syncthreads();

    // gather + classify + emit (lanes<16 own one row per set)
    unsigned* cnt = (unsigned*)(out + CNT_OFF);
    #pragma unroll
    for (int set = 0; set < 2; ++set) {
        bool act = (lane < 16);
        int gidx = nbase + wave * 32 + set * 16 + l16;
        int I1 = set ? k11 : k10;
        int tot = 0, c[4];
        c[0] = c[1] = c[2] = c[3] = I1;            // pad with best (harmless dup)
        if (act) {
            #pragma unroll
            for (int q = 0; q < 4; ++q) {
                unsigned long long pl = lists[wave][set * 16 + l16][q];
                int pc = (int)(pl >> 48);
                #pragma unroll
                for (int j = 0; j < 4; ++j) {
                    int kv = (int)((pl >> (12 * j)) & 4095ull);
                    if (j < pc && tot + j < 4) c[tot + j] = kv;
                }
                tot += pc;
            }
            out[IDX_OFF + gidx] = (float)I1;       // final for clean; placeholder else
        }
        bool cand = act && (tot >= 2) && (tot <= 4);
        bool full = act && (tot > 4);
        unsigned long long mc = __ballot(cand);
        if (mc) {
            int leader = __ffsll((long long)mc) - 1;
            unsigned base = 0;
            if (lane == leader) base = atomicAdd(cnt, (unsigned)__popcll(mc));
            base = __shfl(base, leader);
            if (cand) {
                unsigned pos = base + (unsigned)__popcll(mc & ((1ull << lane) - 1ull));
                reinterpret_cast<uint4*>(out + CAND_OFF)[pos] =
                    make_uint4((unsigned)gidx,
                               (unsigned)c[0] | ((unsigned)c[1] << 16),
                               (unsigned)c[2] | ((unsigned)c[3] << 16), 0u);
            }
        }
        unsigned long long mf = __ballot(full);
        if (mf) {
            int leader = __ffsll((long long)mf) - 1;
            unsigned base = 0;
            if (lane == leader) base = atomicAdd(cnt + 1, (unsigned)__popcll(mf));
            base = __shfl(base, leader);
            if (full) {
                unsigned pos = base + (unsigned)__popcll(mf & ((1ull << lane) - 1ull));
                reinterpret_cast<unsigned*>(out + FULL_OFF)[pos] = (unsigned)gidx;
            }
        }
    }
}

// ---- K2a: candidate rescore (<=4 codes), grid-stride waves (R12-proven) ----
__global__ __launch_bounds__(256) void vq_resolve_cand(const float* __restrict__ z,
                                                       const float* __restrict__ e,
                                                       float* __restrict__ out) {
    const int wave = threadIdx.x >> 6, lane = threadIdx.x & 63;
    const unsigned n = *reinterpret_cast<const unsigned*>(out + CNT_OFF);
    const uint4* list = reinterpret_cast<const uint4*>(out + CAND_OFF);
    for (unsigned ei = blockIdx.x * 4 + wave; ei < n; ei += gridDim.x * 4) {
        uint4 ent = list[ei];
        const int gidx = (int)ent.x;
        const int c1 = (int)(ent.y & 0xFFFFu), c2 = (int)(ent.y >> 16);
        const int c3 = (int)(ent.z & 0xFFFFu), c4 = (int)(ent.z >> 16);
        const int b = gidx >> 14, m = gidx & (MB - 1);
        const float* zr = z + (size_t)b * DIM * MB + m;
        const float* e1 = e + (size_t)c1 * DIM;
        const float* e2 = e + (size_t)c2 * DIM;
        const float* e3 = e + (size_t)c3 * DIM;
        const float* e4 = e + (size_t)c4 * DIM;
        double A = 0.0;
        double d1 = 0.0, d2 = 0.0, d3 = 0.0, d4 = 0.0;
        double q1 = 0.0, q2 = 0.0, q3 = 0.0, q4 = 0.0;
        #pragma unroll
        for (int jj = 0; jj < 4; ++jj) {
            int d = lane * 4 + jj;
            double zv = (double)zr[(size_t)d * MB];
            double v1 = (double)e1[d], v2 = (double)e2[d];
            double v3 = (double)e3[d], v4 = (double)e4[d];
            A = fma(zv, zv, A);
            d1 = fma(zv, v1, d1); q1 = fma(v1, v1, q1);
            d2 = fma(zv, v2, d2); q2 = fma(v2, v2, q2);
            d3 = fma(zv, v3, d3); q3 = fma(v3, v3, q3);
            d4 = fma(zv, v4, d4); q4 = fma(v4, v4, q4);
        }
        #pragma unroll
        for (int mm = 1; mm < 64; mm <<= 1) {
            A += __shfl_xor(A, mm);
            d1 += __shfl_xor(d1, mm); q1 += __shfl_xor(q1, mm);
            d2 += __shfl_xor(d2, mm); q2 += __shfl_xor(q2, mm);
            d3 += __shfl_xor(d3, mm); q3 += __shfl_xor(q3, mm);
            d4 += __shfl_xor(d4, mm); q4 += __shfl_xor(q4, mm);
        }
        if (lane == 0) {
            float Af = (float)A;
            float s1 = (Af - (float)(2.0 * d1)) + (float)q1;
            float s2 = (Af - (float)(2.0 * d2)) + (float)q2;
            float s3 = (Af - (float)(2.0 * d3)) + (float)q3;
            float s4 = (Af - (float)(2.0 * d4)) + (float)q4;
            float bv = s1; int bk = c1;
            if (lexlt(s2, c2, bv, bk)) { bv = s2; bk = c2; }
            if (lexlt(s3, c3, bv, bk)) { bv = s3; bk = c3; }
            if (lexlt(s4, c4, bv, bk)) { bv = s4; bk = c4; }
            out[IDX_OFF + gidx] = (float)bk;
        }
    }
}

// ---- K2b: full exact rescan, grid-stride blocks (R12-proven) ----
__global__ __launch_bounds__(256) void vq_resolve_full(const float* __restrict__ z,
                                                       const float* __restrict__ e,
                                                       float* __restrict__ out) {
    __shared__ float zs[DIM];
    __shared__ float rv[4];
    __shared__ int ri[4];
    const int tid = threadIdx.x;
    const int wave = tid >> 6, lane = tid & 63;
    const unsigned n = reinterpret_cast<const unsigned*>(out + CNT_OFF)[1];
    const unsigned* list = reinterpret_cast<const unsigned*>(out + FULL_OFF);
    for (unsigned ei = blockIdx.x; ei < n; ei += gridDim.x) {
        const int gidx = (int)list[ei];
        const int b = gidx >> 14, m = gidx & (MB - 1);
        const float* zr = z + (size_t)b * DIM * MB + m;
        if (tid < DIM) zs[tid] = zr[(size_t)tid * MB];
        __syncthreads();
        double av = 0.0;
        #pragma unroll
        for (int t2 = 0; t2 < 4; ++t2) {
            double zv = (double)zs[lane * 4 + t2];
            av = fma(zv, zv, av);
        }
        #pragma unroll
        for (int mm = 1; mm < 64; mm <<= 1) av += __shfl_xor(av, mm);
        const float Af = (float)av;

        float bsv = FLT_MAX; int bsk = 0;
        for (int kk = 0; kk < 16; ++kk) {
            const int k = kk * 256 + tid;          // ascending per thread
            const float4* er4 = reinterpret_cast<const float4*>(e + (size_t)k * DIM);
            const float4* zs4 = reinterpret_cast<const float4*>(zs);
            double dot0 = 0.0, dot1 = 0.0, q0 = 0.0, q1 = 0.0;
            #pragma unroll 8
            for (int d4 = 0; d4 < 64; ++d4) {
                float4 ev = er4[d4];
                float4 zv = zs4[d4];
                dot0 = fma((double)zv.x, (double)ev.x, dot0);
                dot1 = fma((double)zv.y, (double)ev.y, dot1);
                dot0 = fma((double)zv.z, (double)ev.z, dot0);
                dot1 = fma((double)zv.w, (double)ev.w, dot1);
                q0 = fma((double)ev.x, (double)ev.x, q0);
                q1 = fma((double)ev.y, (double)ev.y, q1);
                q0 = fma((double)ev.z, (double)ev.z, q0);
                q1 = fma((double)ev.w, (double)ev.w, q1);
            }
            float s = (Af - (float)(2.0 * (dot0 + dot1))) + (float)(q0 + q1);
            if (s < bsv) { bsv = s; bsk = k; }
        }
        #pragma unroll
        for (int mm = 1; mm < 64; mm <<= 1) {
            float ov = __shfl_xor(bsv, mm);
            int oi = __shfl_xor(bsk, mm);
            if (ov < bsv || (ov == bsv && oi < bsk)) { bsv = ov; bsk = oi; }
        }
        if (lane == 0) { rv[wave] = bsv; ri[wave] = bsk; }
        __syncthreads();
        if (tid == 0) {
            float bv = rv[0]; int bk = ri[0];
            #pragma unroll
            for (int wv = 1; wv < 4; ++wv) {
                if (rv[wv] < bv || (rv[wv] == bv && ri[wv] < bk)) { bv = rv[wv]; bk = ri[wv]; }
            }
            out[IDX_OFF + gidx] = (float)bk;
        }
        __syncthreads();
    }
}

// ---- K3: z_q scatter + fused loss; e-rows staged in LDS (R12-proven) ----
__global__ __launch_bounds__(256) void vq_apply(const float* __restrict__ z,
                                                const float* __restrict__ e,
                                                float* __restrict__ out) {
    __shared__ int lds_fi[64];
    __shared__ float lds_e[64][260];
    __shared__ double lds_ls[4];
    const int tid = threadIdx.x;
    const int wave = tid >> 6, lane = tid & 63;
    const int nbase = blockIdx.x * 64;
    const int b = nbase / MB;
    const int mbase = nbase % MB;
    if (tid < 64) lds_fi[tid] = (int)out[IDX_OFF + nbase + tid];
    __syncthreads();
    for (int r = wave; r < 64; r += 4) {
        int code = lds_fi[r];
        float4 v = reinterpret_cast<const float4*>(e + (size_t)code * DIM)[lane];
        *reinterpret_cast<float4*>(&lds_e[r][lane * 4]) = v;
    }
    __syncthreads();

    double lsum = 0.0;
    const int mloc = tid & 63;
    const int d0 = tid >> 6;
    #pragma unroll 4
    for (int d = d0; d < DIM; d += 4) {
        float ev = lds_e[mloc][d];
        size_t off = (size_t)b * (DIM * MB) + (size_t)d * MB + mbase + mloc;
        float zv = z[off];
        out[off] = ev;
        float diff = ev - zv;
        lsum += (double)diff * diff;
    }
    #pragma unroll
    for (int off = 32; off > 0; off >>= 1) lsum += __shfl_down(lsum, off);
    if (lane == 0) lds_ls[wave] = lsum;
    __syncthreads();
    if (tid == 0) {
        double t = lds_ls[0] + lds_ls[1] + lds_ls[2] + lds_ls[3];
        atomicAdd(out + LOSS_OFF, (float)(t * (1.25 / (double)ZELEMS)));
    }
}

extern "C" void kernel_launch(void* const* d_in, const int* in_sizes, int n_in,
                              void* d_out, int out_size, void* d_ws, size_t ws_size,
                              hipStream_t stream) {
    const float* z = (const float*)d_in[0];    // [4,256,16,32,32] fp32
    const float* e = (const float*)d_in[1];    // [4096,256] fp32
    float* out = (float*)d_out;

    hipMemsetAsync(out + LOSS_OFF, 0, sizeof(float), stream);
    hipMemsetAsync(out + CNT_OFF, 0, 2 * sizeof(unsigned), stream);
    vq_prep<<<1536, 256, 0, stream>>>(e, out);
    vq_fast<<<NTOT / 128, 256, 0, stream>>>(z, out);
    vq_resolve_cand<<<256, 256, 0, stream>>>(z, e, out);
    vq_resolve_full<<<512, 256, 0, stream>>>(z, e, out);
    vq_apply<<<NTOT / 64, 256, 0, stream>>>(z, e, out);
}